// Round 2
// baseline (365.387 us; speedup 1.0000x reference)
//
#include <hip/hip_runtime.h>
#include <hip/hip_bf16.h>
#include <cstdint>
#include <cstddef>

#define B_ 4
#define L_ 2048
#define C_ 1024
#define H_ 16
#define D_ 64

typedef __bf16    bf16x2 __attribute__((ext_vector_type(2)));
typedef __bf16    bf16x4 __attribute__((ext_vector_type(4)));
typedef __bf16    bf16x8 __attribute__((ext_vector_type(8)));
typedef _Float16  f16x4  __attribute__((ext_vector_type(4)));
typedef _Float16  f16x8  __attribute__((ext_vector_type(8)));
typedef float     f32x4  __attribute__((ext_vector_type(4)));

// async global->LDS, 16 B per lane. LDS dest = wave-uniform base + lane*16.
typedef const __attribute__((address_space(1))) uint32_t* gas_ptr;
typedef __attribute__((address_space(3))) uint32_t* las_ptr;
__device__ __forceinline__ void gl_lds16(const void* g, void* l) {
    __builtin_amdgcn_global_load_lds((gas_ptr)(uintptr_t)g,
                                     (las_ptr)(uintptr_t)l, 16, 0, 0);
}

// ---------------------------------------------------------------------------
// prep kernel: region A = x fp32->fp16 (8192 blocks), region B = Wqkv
// transpose+cvt (768 blocks), region C = Wout transpose+cvt (256 blocks).
// ---------------------------------------------------------------------------
__global__ __launch_bounds__(256) void prep_kernel(
    const float* __restrict__ x, _Float16* __restrict__ x16,
    const float* __restrict__ Wqkv, _Float16* __restrict__ Wq16,
    const float* __restrict__ Wout, _Float16* __restrict__ Wo16)
{
    __shared__ float tile[64][65];
    int bid = blockIdx.x;
    const int tid = threadIdx.x;

    if (bid < 8192) {                      // cvt x
        int i = (bid * 256 + tid) * 4;
        float4 v = *(const float4*)&x[i];
        f16x4 o = {(_Float16)v.x, (_Float16)v.y, (_Float16)v.z, (_Float16)v.w};
        *(f16x4*)&x16[i] = o;
        return;
    }
    bid -= 8192;
    const float* W; _Float16* Wt; int N, tx, ty;
    if (bid < 768) { W = Wqkv; Wt = Wq16; N = 3072; tx = bid % 48; ty = bid / 48; }
    else { bid -= 768; W = Wout; Wt = Wo16; N = 1024; tx = bid % 16; ty = bid / 16; }
    const int K = 1024;
    const int k0 = ty * 64, n0 = tx * 64;
    for (int i = tid; i < 1024; i += 256) {
        int r = i >> 4, c4 = (i & 15) * 4;
        float4 v = *(const float4*)&W[(size_t)(k0 + r) * N + n0 + c4];
        tile[r][c4 + 0] = v.x; tile[r][c4 + 1] = v.y;
        tile[r][c4 + 2] = v.z; tile[r][c4 + 3] = v.w;
    }
    __syncthreads();
    for (int i = tid; i < 1024; i += 256) {
        int n = i >> 4, k4 = (i & 15) * 4;
        f16x4 o = {(_Float16)tile[k4 + 0][n], (_Float16)tile[k4 + 1][n],
                   (_Float16)tile[k4 + 2][n], (_Float16)tile[k4 + 3][n]};
        *(f16x4*)&Wt[(size_t)(n0 + n) * K + k0 + k4] = o;
    }
}

// ---------------------------------------------------------------------------
// fp16 MFMA GEMM (m97 structure).
// MODE 0: proj — fp32 out + bias.
// MODE 1: QKV fused — q/k tiles: bias + per-head RMS norm on fp32 acc
//   (q scale = log2e, k scale = sqrt(D)=8), write bf16 to qkv;
//   v tiles: bias, bf16, transpose via LDS (aliased over staging), write vT.
// ---------------------------------------------------------------------------
template <int MODE>
__global__ __launch_bounds__(256) void gemm_f16_bt_kernel(
    const _Float16* __restrict__ A, const _Float16* __restrict__ Bt,
    const float* __restrict__ bias, void* __restrict__ Cout,
    __bf16* __restrict__ vTout, const float* __restrict__ q_gamma,
    const float* __restrict__ k_gamma, int M, int N, int K)
{
    __shared__ __align__(16) char smraw[MODE == 1 ? 34816 : 16384];
    _Float16* Ash = (_Float16*)smraw;
    _Float16* Bsh = Ash + 128 * 32;

    const int tid  = threadIdx.x;
    const int lane = tid & 63;
    const int wv   = tid >> 6;
    const int wm   = wv & 1, wn = wv >> 1;
    const int n16  = lane & 15, quad = lane >> 4;
    const int brow = blockIdx.y * 128;
    const int bcol = blockIdx.x * 128;

    const int srow = lane >> 2;
    const int scol = (lane & 3) * 8;
    const _Float16* gA = A  + (size_t)(brow + wv * 32 + srow) * K + scol;
    const _Float16* gB = Bt + (size_t)(bcol + wv * 32 + srow) * K + scol;
    _Float16* lA0 = &Ash[wv * 1024];
    _Float16* lA1 = &Ash[wv * 1024 + 512];
    _Float16* lB0 = &Bsh[wv * 1024];
    _Float16* lB1 = &Bsh[wv * 1024 + 512];

    f32x4 acc[4][4] = {};

    for (int k0 = 0; k0 < K; k0 += 32) {
        gl_lds16(gA + k0,                  lA0);
        gl_lds16(gA + k0 + 16 * (size_t)K, lA1);
        gl_lds16(gB + k0,                  lB0);
        gl_lds16(gB + k0 + 16 * (size_t)K, lB1);
        __syncthreads();

        f16x8 ar[4], br[4];
        #pragma unroll
        for (int t = 0; t < 4; t++) {
            ar[t] = *(const f16x8*)&Ash[(wm * 64 + t * 16 + n16) * 32 + quad * 8];
            br[t] = *(const f16x8*)&Bsh[(wn * 64 + t * 16 + n16) * 32 + quad * 8];
        }
        #pragma unroll
        for (int i = 0; i < 4; i++)
            #pragma unroll
            for (int j = 0; j < 4; j++)
                acc[i][j] = __builtin_amdgcn_mfma_f32_16x16x32_f16(
                    ar[i], br[j], acc[i][j], 0, 0, 0);
        __syncthreads();
    }

    if (MODE == 0) {
        #pragma unroll
        for (int j = 0; j < 4; j++) {
            const int col = bcol + wn * 64 + j * 16 + n16;
            const float bv = bias[col];
            #pragma unroll
            for (int i = 0; i < 4; i++) {
                const int row0 = brow + wm * 64 + i * 16 + quad * 4;
                #pragma unroll
                for (int r = 0; r < 4; r++)
                    ((float*)Cout)[(size_t)(row0 + r) * N + col] = acc[i][j][r] + bv;
            }
        }
        return;
    }

    // ---------------- MODE 1: fused QKV epilogue ----------------
    const int region = bcol >> 10;         // 0 = q, 1 = k, 2 = v
    float bj[4];
    #pragma unroll
    for (int j = 0; j < 4; j++) bj[j] = bias[bcol + wn * 64 + j * 16 + n16];

    if (region < 2) {
        const float* gamma = (region == 0) ? q_gamma : k_gamma;
        const float scl = (region == 0) ? 1.44269504f : 8.0f;  // log2e | sqrt(D)
        const int cb = (bcol & 1023) + wn * 64 + n16;          // head-local col
        float gj[4];
        #pragma unroll
        for (int j = 0; j < 4; j++) gj[j] = gamma[cb + j * 16];

        #pragma unroll
        for (int i = 0; i < 4; i++) {
            #pragma unroll
            for (int r = 0; r < 4; r++) {
                float v0 = acc[i][0][r] + bj[0];
                float v1 = acc[i][1][r] + bj[1];
                float v2 = acc[i][2][r] + bj[2];
                float v3 = acc[i][3][r] + bj[3];
                float ss = v0 * v0 + v1 * v1 + v2 * v2 + v3 * v3;
                ss += __shfl_xor(ss, 1, 64);
                ss += __shfl_xor(ss, 2, 64);
                ss += __shfl_xor(ss, 4, 64);
                ss += __shfl_xor(ss, 8, 64);
                const float sc = scl / fmaxf(sqrtf(ss), 1e-12f);
                const int row = brow + wm * 64 + i * 16 + quad * 4 + r;
                __bf16* op = (__bf16*)Cout + (size_t)row * 3072 + bcol + wn * 64 + n16;
                op[ 0] = (__bf16)(v0 * gj[0] * sc);
                op[16] = (__bf16)(v1 * gj[1] * sc);
                op[32] = (__bf16)(v2 * gj[2] * sc);
                op[48] = (__bf16)(v3 * gj[3] * sc);
            }
        }
    } else {
        // v region: bias + bf16, transpose via LDS, store to vT[b][h][d][l]
        __syncthreads();                       // staging reads done; reuse LDS
        __bf16* LT = (__bf16*)smraw;           // [col 0..127][row 0..127] s=136
        #pragma unroll
        for (int i = 0; i < 4; i++)
            #pragma unroll
            for (int j = 0; j < 4; j++) {
                const int col = wn * 64 + j * 16 + n16;
                const int row0 = wm * 64 + i * 16 + quad * 4;
                bf16x4 t4 = {(__bf16)(acc[i][j][0] + bj[j]),
                             (__bf16)(acc[i][j][1] + bj[j]),
                             (__bf16)(acc[i][j][2] + bj[j]),
                             (__bf16)(acc[i][j][3] + bj[j])};
                *(bf16x4*)&LT[col * 136 + row0] = t4;
            }
        __syncthreads();
        const int d = tid >> 1, hf = tid & 1;
        const int bidx = brow >> 11;           // batch
        const int l0 = (brow & 2047) + hf * 64;
        const int head = ((bcol - 2048) >> 6) + (d >> 6);
        const size_t vb = (((size_t)(bidx * 16 + head)) * 64 + (d & 63)) * 2048 + l0;
        #pragma unroll
        for (int u = 0; u < 8; u++)
            *(bf16x8*)&vTout[vb + u * 8] = *(const bf16x8*)&LT[d * 136 + hf * 64 + u * 8];
    }
}

// ---------------------------------------------------------------------------
// MFMA flash attention v5: Bq=128, no-max softmax (|s_log2| <= 11.6, safe).
// S^T = K @ Q^T; O^T = V^T @ P^T.
// R1 changes vs v4 (theory: LDS pipe is the bottleneck + 3-block/CU tail):
//  - V fragments read DIRECTLY from global vT (contiguous bf16x8; all 4
//    waves of a block read identical addresses -> L1-served, tile 8 KB).
//    Removes 8 b128 LDS reads + V staging per iter (~40% of LDS traffic).
//    Loads issued right after QK^T so softmax+P-roundtrip hides latency.
//  - Q fragments read directly from global (one-time, contiguous 16 B);
//    Q staging + prologue barrier removed.
//  - LDS 50 KB -> 34.8 KB (P scratch 18.4K + K dbuf 16K): 4 blocks/CU,
//    grid 1024 = 4 x 256 CUs -> zero tail. launch_bounds(256,4) pins
//    VGPR <= 128 to keep 4 blocks resident.
//  - K staging (global_load_lds, chunk-swizzled source) + double-buffer
//    + setprio unchanged.
// ---------------------------------------------------------------------------
__global__ __launch_bounds__(256, 4) void attn_mfma_kernel(
    const __bf16* __restrict__ qkv, const __bf16* __restrict__ vT,
    _Float16* __restrict__ h16)
{
    const int tid  = threadIdx.x;
    const int lane = tid & 63;
    const int wv   = tid >> 6;
    const int n16  = lane & 15;
    const int quad = lane >> 4;
    const int qt = blockIdx.x & 15;
    const int hh = (blockIdx.x >> 4) & 15;
    const int bb = blockIdx.x >> 8;
    const int q0 = qt * 128;
    const int w32 = wv * 32;
    const int bh = bb * 16 + hh;

    __shared__ __align__(16) __bf16 smem[128 * 72 + 2 * 64 * 64];
    __bf16* QP   = smem;                    // P scratch, 128 x 72
    __bf16* Kbuf = smem + 128 * 72;         // 2 x [64][64] chunk-swizzled

    const __bf16* kbase = &qkv[(size_t)(bb * L_) * 3072 + 1024 + hh * 64];
    const __bf16* vbase = &vT[(size_t)bh * 64 * 2048];

    // K staging: per-lane chunk-swizzled global source, linear LDS dest
    const int lr = lane >> 3;               // row-in-group 0..7
    const int lc = (lane & 7) ^ lr;         // swizzled 16B chunk
    const __bf16* kpre = kbase + (size_t)(wv * 8 + lr) * 3072 + lc * 8;
    __bf16* kdst = Kbuf + (wv * 8) * 64;

    // prologue: stage K tile 0 (async)
    #pragma unroll
    for (int t = 0; t < 2; t++)
        gl_lds16(kpre + (size_t)t * 32 * 3072, kdst + t * 2048);

    // Q fragments direct from global (contiguous 16 B per lane)
    bf16x8 qf[2][2];
    const __bf16* qrow = &qkv[(size_t)(bb * L_ + q0 + w32 + n16) * 3072 + hh * 64 + quad * 8];
    #pragma unroll
    for (int qg = 0; qg < 2; qg++)
        #pragma unroll
        for (int hf = 0; hf < 2; hf++)
            qf[qg][hf] = *(const bf16x8*)&qrow[(size_t)qg * 16 * 3072 + hf * 32];

    // per-lane V base (vT[d][l], rows d = dg*16+n16)
    const __bf16* vrow = vbase + (size_t)n16 * 2048 + quad * 8;

    f32x4 O[2][4] = {};
    float l_run[2] = {0.f, 0.f};

    // swizzled K read offsets (elements): row*64 + (chunk ^ (row&7))*16B
    const int bk0 = n16 * 64 + ((quad)     ^ (n16 & 7)) * 8;   // chunks 0..3
    const int bk1 = n16 * 64 + ((quad + 4) ^ (n16 & 7)) * 8;   // chunks 4..7

    __syncthreads();   // K tile 0 staged (barrier drains vmcnt)

    for (int j0 = 0, cur = 0; j0 < L_; j0 += 64, cur ^= 1) {
        // prefetch next K tile into the other buffer (hidden under compute)
        if (j0 + 64 < L_) {
            const __bf16* kp = kpre + (size_t)(j0 + 64) * 3072;
            __bf16* kd = kdst + (cur ^ 1) * 4096;
            #pragma unroll
            for (int t = 0; t < 2; t++)
                gl_lds16(kp + (size_t)t * 32 * 3072, kd + t * 2048);
        }
        const __bf16* Kc = Kbuf + cur * 4096;

        f32x4 St[2][4] = {};
        __builtin_amdgcn_s_setprio(1);
        #pragma unroll
        for (int kg = 0; kg < 4; kg++) {
            bf16x8 a0 = *(const bf16x8*)&Kc[kg * 1024 + bk0];
            bf16x8 a1 = *(const bf16x8*)&Kc[kg * 1024 + bk1];
            St[0][kg] = __builtin_amdgcn_mfma_f32_16x16x32_bf16(a0, qf[0][0], St[0][kg], 0, 0, 0);
            St[0][kg] = __builtin_amdgcn_mfma_f32_16x16x32_bf16(a1, qf[0][1], St[0][kg], 0, 0, 0);
            St[1][kg] = __builtin_amdgcn_mfma_f32_16x16x32_bf16(a0, qf[1][0], St[1][kg], 0, 0, 0);
            St[1][kg] = __builtin_amdgcn_mfma_f32_16x16x32_bf16(a1, qf[1][1], St[1][kg], 0, 0, 0);
        }
        __builtin_amdgcn_s_setprio(0);

        // V fragments for THIS tile, direct from global (L1/L2-resident);
        // latency hides under softmax + P round-trip below.
        bf16x8 vf[4][2];
        #pragma unroll
        for (int dg = 0; dg < 4; dg++)
            #pragma unroll
            for (int kh = 0; kh < 2; kh++)
                vf[dg][kh] = *(const bf16x8*)&vrow[(size_t)dg * 16 * 2048 + j0 + kh * 32];

        #pragma unroll
        for (int qg = 0; qg < 2; qg++) {
            const int prow = (w32 + qg * 16 + n16) * 72;
            float ts = 0.f;
            #pragma unroll
            for (int kg = 0; kg < 4; kg++) {
                float p0 = __builtin_amdgcn_exp2f(St[qg][kg][0]);
                float p1 = __builtin_amdgcn_exp2f(St[qg][kg][1]);
                float p2 = __builtin_amdgcn_exp2f(St[qg][kg][2]);
                float p3 = __builtin_amdgcn_exp2f(St[qg][kg][3]);
                bf16x4 t4 = {(__bf16)p0, (__bf16)p1, (__bf16)p2, (__bf16)p3};
                *(bf16x4*)&QP[prow + kg * 16 + quad * 4] = t4;
                ts += (p0 + p1) + (p2 + p3);
            }
            ts += __shfl_xor(ts, 16, 64);
            ts += __shfl_xor(ts, 32, 64);
            l_run[qg] += ts;
        }

        bf16x8 pf[2][2];
        #pragma unroll
        for (int qg = 0; qg < 2; qg++)
            #pragma unroll
            for (int kh = 0; kh < 2; kh++)
                pf[qg][kh] = *(const bf16x8*)&QP[(w32 + qg * 16 + n16) * 72 + kh * 32 + quad * 8];

        __builtin_amdgcn_s_setprio(1);
        #pragma unroll
        for (int dg = 0; dg < 4; dg++) {
            O[0][dg] = __builtin_amdgcn_mfma_f32_16x16x32_bf16(vf[dg][0], pf[0][0], O[0][dg], 0, 0, 0);
            O[0][dg] = __builtin_amdgcn_mfma_f32_16x16x32_bf16(vf[dg][1], pf[0][1], O[0][dg], 0, 0, 0);
            O[1][dg] = __builtin_amdgcn_mfma_f32_16x16x32_bf16(vf[dg][0], pf[1][0], O[1][dg], 0, 0, 0);
            O[1][dg] = __builtin_amdgcn_mfma_f32_16x16x32_bf16(vf[dg][1], pf[1][1], O[1][dg], 0, 0, 0);
        }
        __builtin_amdgcn_s_setprio(0);

        __syncthreads();   // drains K prefetch vmcnt + releases buf[cur]
    }

    #pragma unroll
    for (int qg = 0; qg < 2; qg++) {
        const float linv = 1.0f / l_run[qg];
        const int q = q0 + w32 + qg * 16 + n16;
        const size_t orow = (size_t)(bb * L_ + q) * 1024 + hh * 64 + quad * 4;
        #pragma unroll
        for (int dg = 0; dg < 4; dg++) {
            f16x4 o = {(_Float16)(O[qg][dg][0] * linv),
                       (_Float16)(O[qg][dg][1] * linv),
                       (_Float16)(O[qg][dg][2] * linv),
                       (_Float16)(O[qg][dg][3] * linv)};
            *(f16x4*)&h16[orow + dg * 16] = o;
        }
    }
}

// ---------------------------------------------------------------------------
extern "C" void kernel_launch(void* const* d_in, const int* in_sizes, int n_in,
                              void* d_out, int out_size, void* d_ws, size_t ws_size,
                              hipStream_t stream)
{
    const float* x       = (const float*)d_in[0];
    const float* Wqkv    = (const float*)d_in[1];
    const float* bqkv    = (const float*)d_in[2];
    const float* q_gamma = (const float*)d_in[3];
    const float* k_gamma = (const float*)d_in[4];
    const float* Wout    = (const float*)d_in[5];
    const float* bout    = (const float*)d_in[6];
    float* out = (float*)d_out;

    uint8_t* ws = (uint8_t*)d_ws;
    _Float16* x16   = (_Float16*)(ws);                      // 16 MB
    _Float16* Wq16  = (_Float16*)(ws + (16ull << 20));      //  6 MB
    _Float16* Wo16  = (_Float16*)(ws + (22ull << 20));      //  2 MB
    __bf16*   qkv16 = (__bf16*)  (ws + (24ull << 20));      // 48 MB (q,k used)
    _Float16* h16   = (_Float16*)(ws + (72ull << 20));      // 16 MB
    __bf16*   vT    = (__bf16*)  (ws + (88ull << 20));      // 16 MB (total 104)

    // 1) prep: x->fp16, W transposes (one launch, 3 regions)
    prep_kernel<<<8192 + 768 + 256, 256, 0, stream>>>(x, x16, Wqkv, Wq16, Wout, Wo16);

    // 2) fused QKV: GEMM + bias + RMS-norm (q,k -> qkv16 bf16) + V transpose
    gemm_f16_bt_kernel<1><<<dim3(3 * C_ / 128, B_ * L_ / 128), 256, 0, stream>>>(
        x16, Wq16, bqkv, qkv16, vT, q_gamma, k_gamma, B_ * L_, 3 * C_, C_);

    // 3) flash attention (Bq=128, K dbuf in LDS, V direct) -> h16
    attn_mfma_kernel<<<B_ * H_ * (L_ / 128), 256, 0, stream>>>(qkv16, vT, h16);

    // 4) out = h @ Wout + bout -> fp32
    gemm_f16_bt_kernel<0><<<dim3(C_ / 128, B_ * L_ / 128), 256, 0, stream>>>(
        h16, Wo16, bout, out, nullptr, nullptr, nullptr, B_ * L_, C_, C_);
}

// Round 5
// 305.024 us; speedup vs baseline: 1.1979x; 1.1979x over previous
//
#include <hip/hip_runtime.h>
#include <hip/hip_bf16.h>
#include <cstdint>
#include <cstddef>

#define B_ 4
#define L_ 2048
#define C_ 1024
#define H_ 16
#define D_ 64

typedef __bf16    bf16x2 __attribute__((ext_vector_type(2)));
typedef __bf16    bf16x4 __attribute__((ext_vector_type(4)));
typedef __bf16    bf16x8 __attribute__((ext_vector_type(8)));
typedef _Float16  f16x4  __attribute__((ext_vector_type(4)));
typedef _Float16  f16x8  __attribute__((ext_vector_type(8)));
typedef float     f32x4  __attribute__((ext_vector_type(4)));

// async global->LDS, 16 B per lane. LDS dest = wave-uniform base + lane*16.
typedef const __attribute__((address_space(1))) uint32_t* gas_ptr;
typedef __attribute__((address_space(3))) uint32_t* las_ptr;
__device__ __forceinline__ void gl_lds16(const void* g, void* l) {
    __builtin_amdgcn_global_load_lds((gas_ptr)(uintptr_t)g,
                                     (las_ptr)(uintptr_t)l, 16, 0, 0);
}

// ---------------------------------------------------------------------------
// prep kernel: region A = x fp32->fp16 (8192 blocks), region B = Wqkv
// transpose+cvt (768 blocks), region C = Wout transpose+cvt (256 blocks).
// ---------------------------------------------------------------------------
__global__ __launch_bounds__(256) void prep_kernel(
    const float* __restrict__ x, _Float16* __restrict__ x16,
    const float* __restrict__ Wqkv, _Float16* __restrict__ Wq16,
    const float* __restrict__ Wout, _Float16* __restrict__ Wo16)
{
    __shared__ float tile[64][65];
    int bid = blockIdx.x;
    const int tid = threadIdx.x;

    if (bid < 8192) {                      // cvt x
        int i = (bid * 256 + tid) * 4;
        float4 v = *(const float4*)&x[i];
        f16x4 o = {(_Float16)v.x, (_Float16)v.y, (_Float16)v.z, (_Float16)v.w};
        *(f16x4*)&x16[i] = o;
        return;
    }
    bid -= 8192;
    const float* W; _Float16* Wt; int N, tx, ty;
    if (bid < 768) { W = Wqkv; Wt = Wq16; N = 3072; tx = bid % 48; ty = bid / 48; }
    else { bid -= 768; W = Wout; Wt = Wo16; N = 1024; tx = bid % 16; ty = bid / 16; }
    const int K = 1024;
    const int k0 = ty * 64, n0 = tx * 64;
    for (int i = tid; i < 1024; i += 256) {
        int r = i >> 4, c4 = (i & 15) * 4;
        float4 v = *(const float4*)&W[(size_t)(k0 + r) * N + n0 + c4];
        tile[r][c4 + 0] = v.x; tile[r][c4 + 1] = v.y;
        tile[r][c4 + 2] = v.z; tile[r][c4 + 3] = v.w;
    }
    __syncthreads();
    for (int i = tid; i < 1024; i += 256) {
        int n = i >> 4, k4 = (i & 15) * 4;
        f16x4 o = {(_Float16)tile[k4 + 0][n], (_Float16)tile[k4 + 1][n],
                   (_Float16)tile[k4 + 2][n], (_Float16)tile[k4 + 3][n]};
        *(f16x4*)&Wt[(size_t)(n0 + n) * K + k0 + k4] = o;
    }
}

// ---------------------------------------------------------------------------
// fp16 MFMA GEMM (m97 structure).
// MODE 0: proj — fp32 out + bias.
// MODE 1: QKV fused — q/k tiles: bias + per-head RMS norm on fp32 acc
//   (q scale = log2e, k scale = sqrt(D)=8), write bf16 to qkv;
//   v tiles: bias, bf16, transpose via LDS (aliased over staging), write vT.
// ---------------------------------------------------------------------------
template <int MODE>
__global__ __launch_bounds__(256) void gemm_f16_bt_kernel(
    const _Float16* __restrict__ A, const _Float16* __restrict__ Bt,
    const float* __restrict__ bias, void* __restrict__ Cout,
    __bf16* __restrict__ vTout, const float* __restrict__ q_gamma,
    const float* __restrict__ k_gamma, int M, int N, int K)
{
    __shared__ __align__(16) char smraw[MODE == 1 ? 34816 : 16384];
    _Float16* Ash = (_Float16*)smraw;
    _Float16* Bsh = Ash + 128 * 32;

    const int tid  = threadIdx.x;
    const int lane = tid & 63;
    const int wv   = tid >> 6;
    const int wm   = wv & 1, wn = wv >> 1;
    const int n16  = lane & 15, quad = lane >> 4;
    const int brow = blockIdx.y * 128;
    const int bcol = blockIdx.x * 128;

    const int srow = lane >> 2;
    const int scol = (lane & 3) * 8;
    const _Float16* gA = A  + (size_t)(brow + wv * 32 + srow) * K + scol;
    const _Float16* gB = Bt + (size_t)(bcol + wv * 32 + srow) * K + scol;
    _Float16* lA0 = &Ash[wv * 1024];
    _Float16* lA1 = &Ash[wv * 1024 + 512];
    _Float16* lB0 = &Bsh[wv * 1024];
    _Float16* lB1 = &Bsh[wv * 1024 + 512];

    f32x4 acc[4][4] = {};

    for (int k0 = 0; k0 < K; k0 += 32) {
        gl_lds16(gA + k0,                  lA0);
        gl_lds16(gA + k0 + 16 * (size_t)K, lA1);
        gl_lds16(gB + k0,                  lB0);
        gl_lds16(gB + k0 + 16 * (size_t)K, lB1);
        __syncthreads();

        f16x8 ar[4], br[4];
        #pragma unroll
        for (int t = 0; t < 4; t++) {
            ar[t] = *(const f16x8*)&Ash[(wm * 64 + t * 16 + n16) * 32 + quad * 8];
            br[t] = *(const f16x8*)&Bsh[(wn * 64 + t * 16 + n16) * 32 + quad * 8];
        }
        #pragma unroll
        for (int i = 0; i < 4; i++)
            #pragma unroll
            for (int j = 0; j < 4; j++)
                acc[i][j] = __builtin_amdgcn_mfma_f32_16x16x32_f16(
                    ar[i], br[j], acc[i][j], 0, 0, 0);
        __syncthreads();
    }

    if (MODE == 0) {
        #pragma unroll
        for (int j = 0; j < 4; j++) {
            const int col = bcol + wn * 64 + j * 16 + n16;
            const float bv = bias[col];
            #pragma unroll
            for (int i = 0; i < 4; i++) {
                const int row0 = brow + wm * 64 + i * 16 + quad * 4;
                #pragma unroll
                for (int r = 0; r < 4; r++)
                    ((float*)Cout)[(size_t)(row0 + r) * N + col] = acc[i][j][r] + bv;
            }
        }
        return;
    }

    // ---------------- MODE 1: fused QKV epilogue ----------------
    const int region = bcol >> 10;         // 0 = q, 1 = k, 2 = v
    float bj[4];
    #pragma unroll
    for (int j = 0; j < 4; j++) bj[j] = bias[bcol + wn * 64 + j * 16 + n16];

    if (region < 2) {
        const float* gamma = (region == 0) ? q_gamma : k_gamma;
        const float scl = (region == 0) ? 1.44269504f : 8.0f;  // log2e | sqrt(D)
        const int cb = (bcol & 1023) + wn * 64 + n16;          // head-local col
        float gj[4];
        #pragma unroll
        for (int j = 0; j < 4; j++) gj[j] = gamma[cb + j * 16];

        #pragma unroll
        for (int i = 0; i < 4; i++) {
            #pragma unroll
            for (int r = 0; r < 4; r++) {
                float v0 = acc[i][0][r] + bj[0];
                float v1 = acc[i][1][r] + bj[1];
                float v2 = acc[i][2][r] + bj[2];
                float v3 = acc[i][3][r] + bj[3];
                float ss = v0 * v0 + v1 * v1 + v2 * v2 + v3 * v3;
                ss += __shfl_xor(ss, 1, 64);
                ss += __shfl_xor(ss, 2, 64);
                ss += __shfl_xor(ss, 4, 64);
                ss += __shfl_xor(ss, 8, 64);
                const float sc = scl / fmaxf(sqrtf(ss), 1e-12f);
                const int row = brow + wm * 64 + i * 16 + quad * 4 + r;
                __bf16* op = (__bf16*)Cout + (size_t)row * 3072 + bcol + wn * 64 + n16;
                op[ 0] = (__bf16)(v0 * gj[0] * sc);
                op[16] = (__bf16)(v1 * gj[1] * sc);
                op[32] = (__bf16)(v2 * gj[2] * sc);
                op[48] = (__bf16)(v3 * gj[3] * sc);
            }
        }
    } else {
        // v region: bias + bf16, transpose via LDS, store to vT[b][h][d][l]
        __syncthreads();                       // staging reads done; reuse LDS
        __bf16* LT = (__bf16*)smraw;           // [col 0..127][row 0..127] s=136
        #pragma unroll
        for (int i = 0; i < 4; i++)
            #pragma unroll
            for (int j = 0; j < 4; j++) {
                const int col = wn * 64 + j * 16 + n16;
                const int row0 = wm * 64 + i * 16 + quad * 4;
                bf16x4 t4 = {(__bf16)(acc[i][j][0] + bj[j]),
                             (__bf16)(acc[i][j][1] + bj[j]),
                             (__bf16)(acc[i][j][2] + bj[j]),
                             (__bf16)(acc[i][j][3] + bj[j])};
                *(bf16x4*)&LT[col * 136 + row0] = t4;
            }
        __syncthreads();
        const int d = tid >> 1, hf = tid & 1;
        const int bidx = brow >> 11;           // batch
        const int l0 = (brow & 2047) + hf * 64;
        const int head = ((bcol - 2048) >> 6) + (d >> 6);
        const size_t vb = (((size_t)(bidx * 16 + head)) * 64 + (d & 63)) * 2048 + l0;
        #pragma unroll
        for (int u = 0; u < 8; u++)
            *(bf16x8*)&vTout[vb + u * 8] = *(const bf16x8*)&LT[d * 136 + hf * 64 + u * 8];
    }
}

// ---------------------------------------------------------------------------
// MFMA flash attention v7: Bq=128, no-max softmax (|s_log2| <= 11.6, safe).
// S^T = K @ Q^T; O^T = V^T @ P^T.
// R3 post-mortem: single-buffer 2-barrier schedule FAILED correctness
// (absmax 6.7e-3) -> reverted to the R1-PROVEN sync skeleton:
// double-buffered K AND V, prefetch at loop top into buf[cur^1], ONE
// __syncthreads per iteration (drains prefetch + releases buf[cur]).
// R4/R5 change is PARAMETRIC only (R4 bench was an infra failure; source
// re-audited statically and resubmitted unchanged): KV tile 64 -> 32
// tokens, P scratch stride 72x64 -> 40x32:
//   LDS = P 10 KB + K dbuf 8 KB + V dbuf 8 KB = 26.6 KB
//   -> 6 blocks/CU capacity, grid 1024 = 4/CU resident, ZERO tail
//      (R1 measured 24% occupancy: 50 KB -> 3/CU -> 768+256 straggler tail).
// K tile [32 tok][64 d], 8-chunk XOR swizzle (chunk ^ row&7, as R1).
// V tile [64 d][32 tok], 4-chunk XOR swizzle (chunk ^ row&3).
// 16 MFMA/iter x 64 iters (same total), 2 gl_lds/wave/iter (same traffic).
// ---------------------------------------------------------------------------
__global__ __launch_bounds__(256, 4) void attn_mfma_kernel(
    const __bf16* __restrict__ qkv, const __bf16* __restrict__ vT,
    _Float16* __restrict__ h16)
{
    const int tid  = threadIdx.x;
    const int lane = tid & 63;
    const int wv   = tid >> 6;
    const int n16  = lane & 15;
    const int quad = lane >> 4;
    const int qt = blockIdx.x & 15;
    const int hh = (blockIdx.x >> 4) & 15;
    const int bb = blockIdx.x >> 8;
    const int q0 = qt * 128;
    const int w32 = wv * 32;
    const int bh = bb * 16 + hh;

    __shared__ __align__(16) __bf16 smem[128 * 40 + 2 * 2048 + 2 * 2048]; // 26624 B
    __bf16* QP   = smem;                    // P scratch, 128 x 40 (wave-private rows)
    __bf16* Kbuf = smem + 5120;             // 2 x [32 tok][64 d], chunk-swizzled
    __bf16* Vbuf = smem + 5120 + 4096;      // 2 x [64 d][32 tok], chunk-swizzled

    const __bf16* kbase = &qkv[(size_t)(bb * L_) * 3072 + 1024 + hh * 64];
    const __bf16* vbase = &vT[(size_t)bh * 64 * 2048];

    // K staging: rows = tokens (32, 128 B each). lane -> row wv*8+(lane>>3),
    // source chunk (lane&7)^(row&7); LDS dest linear.
    const int klr = lane >> 3;
    const int klc = (lane & 7) ^ klr;
    const __bf16* kpre = kbase + (size_t)(wv * 8 + klr) * 3072 + klc * 8;
    __bf16* kdst = Kbuf + (wv * 8) * 64;

    // V staging: rows = d (64, 64 B each). lane -> row wv*16+(lane>>2),
    // source chunk (lane&3)^(row&3); LDS dest linear.
    const int vlr = lane >> 2;
    const int vlc = (lane & 3) ^ (vlr & 3);
    const __bf16* vpre = vbase + (size_t)(wv * 16 + vlr) * 2048 + vlc * 8;
    __bf16* vdst = Vbuf + (wv * 16) * 32;

    // prologue: stage K[0], V[0] into buffer 0 (async)
    gl_lds16(kpre, kdst);
    gl_lds16(vpre, vdst);

    // Q fragments direct from global (one-time; verified R2)
    bf16x8 qf[2][2];
    const __bf16* qrow = &qkv[(size_t)(bb * L_ + q0 + w32 + n16) * 3072 + hh * 64 + quad * 8];
    #pragma unroll
    for (int qg = 0; qg < 2; qg++)
        #pragma unroll
        for (int hf = 0; hf < 2; hf++)
            qf[qg][hf] = *(const bf16x8*)&qrow[(size_t)qg * 16 * 3072 + hf * 32];

    f32x4 O[2][4] = {};
    float l_run[2] = {0.f, 0.f};

    // swizzled read offsets (elements)
    const int bk0 = n16 * 64 + ((quad)     ^ (n16 & 7)) * 8;   // K chunks 0..3
    const int bk1 = n16 * 64 + ((quad + 4) ^ (n16 & 7)) * 8;   // K chunks 4..7
    const int bv0 = n16 * 32 + ((quad)     ^ (n16 & 3)) * 8;   // V chunks 0..3

    __syncthreads();   // drains K[0], V[0]

    for (int j0 = 0, cur = 0; j0 < L_; j0 += 32, cur ^= 1) {
        // prefetch next tile into the other buffer (R1-proven pattern)
        if (j0 + 32 < L_) {
            gl_lds16(kpre + (size_t)(j0 + 32) * 3072, kdst + (cur ^ 1) * 2048);
            gl_lds16(vpre + (j0 + 32),                vdst + (cur ^ 1) * 2048);
        }
        const __bf16* Kc = Kbuf + cur * 2048;
        const __bf16* Vc = Vbuf + cur * 2048;

        // ---- QK^T ----
        f32x4 St[2][2] = {};
        __builtin_amdgcn_s_setprio(1);
        #pragma unroll
        for (int kg = 0; kg < 2; kg++) {
            bf16x8 a0 = *(const bf16x8*)&Kc[kg * 1024 + bk0];
            bf16x8 a1 = *(const bf16x8*)&Kc[kg * 1024 + bk1];
            St[0][kg] = __builtin_amdgcn_mfma_f32_16x16x32_bf16(a0, qf[0][0], St[0][kg], 0, 0, 0);
            St[0][kg] = __builtin_amdgcn_mfma_f32_16x16x32_bf16(a1, qf[0][1], St[0][kg], 0, 0, 0);
            St[1][kg] = __builtin_amdgcn_mfma_f32_16x16x32_bf16(a0, qf[1][0], St[1][kg], 0, 0, 0);
            St[1][kg] = __builtin_amdgcn_mfma_f32_16x16x32_bf16(a1, qf[1][1], St[1][kg], 0, 0, 0);
        }
        __builtin_amdgcn_s_setprio(0);

        // ---- softmax + P write (wave-private QP rows; no barrier needed) ----
        #pragma unroll
        for (int qg = 0; qg < 2; qg++) {
            const int prow = (w32 + qg * 16 + n16) * 40;
            float ts = 0.f;
            #pragma unroll
            for (int kg = 0; kg < 2; kg++) {
                float p0 = __builtin_amdgcn_exp2f(St[qg][kg][0]);
                float p1 = __builtin_amdgcn_exp2f(St[qg][kg][1]);
                float p2 = __builtin_amdgcn_exp2f(St[qg][kg][2]);
                float p3 = __builtin_amdgcn_exp2f(St[qg][kg][3]);
                bf16x4 t4 = {(__bf16)p0, (__bf16)p1, (__bf16)p2, (__bf16)p3};
                *(bf16x4*)&QP[prow + kg * 16 + quad * 4] = t4;
                ts += (p0 + p1) + (p2 + p3);
            }
            ts += __shfl_xor(ts, 16, 64);
            ts += __shfl_xor(ts, 32, 64);
            l_run[qg] += ts;
        }

        // ---- P frags + PV ----
        bf16x8 pf[2];
        #pragma unroll
        for (int qg = 0; qg < 2; qg++)
            pf[qg] = *(const bf16x8*)&QP[(w32 + qg * 16 + n16) * 40 + quad * 8];

        __builtin_amdgcn_s_setprio(1);
        #pragma unroll
        for (int dg = 0; dg < 4; dg++) {
            bf16x8 v0 = *(const bf16x8*)&Vc[dg * 512 + bv0];
            O[0][dg] = __builtin_amdgcn_mfma_f32_16x16x32_bf16(v0, pf[0], O[0][dg], 0, 0, 0);
            O[1][dg] = __builtin_amdgcn_mfma_f32_16x16x32_bf16(v0, pf[1], O[1][dg], 0, 0, 0);
        }
        __builtin_amdgcn_s_setprio(0);

        __syncthreads();   // drains prefetch vmcnt + releases buf[cur]
    }

    #pragma unroll
    for (int qg = 0; qg < 2; qg++) {
        const float linv = 1.0f / l_run[qg];
        const int q = q0 + w32 + qg * 16 + n16;
        const size_t orow = (size_t)(bb * L_ + q) * 1024 + hh * 64 + quad * 4;
        #pragma unroll
        for (int dg = 0; dg < 4; dg++) {
            f16x4 o = {(_Float16)(O[qg][dg][0] * linv),
                       (_Float16)(O[qg][dg][1] * linv),
                       (_Float16)(O[qg][dg][2] * linv),
                       (_Float16)(O[qg][dg][3] * linv)};
            *(f16x4*)&h16[orow + dg * 16] = o;
        }
    }
}

// ---------------------------------------------------------------------------
extern "C" void kernel_launch(void* const* d_in, const int* in_sizes, int n_in,
                              void* d_out, int out_size, void* d_ws, size_t ws_size,
                              hipStream_t stream)
{
    const float* x       = (const float*)d_in[0];
    const float* Wqkv    = (const float*)d_in[1];
    const float* bqkv    = (const float*)d_in[2];
    const float* q_gamma = (const float*)d_in[3];
    const float* k_gamma = (const float*)d_in[4];
    const float* Wout    = (const float*)d_in[5];
    const float* bout    = (const float*)d_in[6];
    float* out = (float*)d_out;

    uint8_t* ws = (uint8_t*)d_ws;
    _Float16* x16   = (_Float16*)(ws);                      // 16 MB
    _Float16* Wq16  = (_Float16*)(ws + (16ull << 20));      //  6 MB
    _Float16* Wo16  = (_Float16*)(ws + (22ull << 20));      //  2 MB
    __bf16*   qkv16 = (__bf16*)  (ws + (24ull << 20));      // 48 MB (q,k used)
    _Float16* h16   = (_Float16*)(ws + (72ull << 20));      // 16 MB
    __bf16*   vT    = (__bf16*)  (ws + (88ull << 20));      // 16 MB (total 104)

    // 1) prep: x->fp16, W transposes (one launch, 3 regions)
    prep_kernel<<<8192 + 768 + 256, 256, 0, stream>>>(x, x16, Wqkv, Wq16, Wout, Wo16);

    // 2) fused QKV: GEMM + bias + RMS-norm (q,k -> qkv16 bf16) + V transpose
    gemm_f16_bt_kernel<1><<<dim3(3 * C_ / 128, B_ * L_ / 128), 256, 0, stream>>>(
        x16, Wq16, bqkv, qkv16, vT, q_gamma, k_gamma, B_ * L_, 3 * C_, C_);

    // 3) flash attention (Bq=128, 32-token K/V tiles, dbuf, 4+ blocks/CU) -> h16
    attn_mfma_kernel<<<B_ * H_ * (L_ / 128), 256, 0, stream>>>(qkv16, vT, h16);

    // 4) out = h @ Wout + bout -> fp32
    gemm_f16_bt_kernel<0><<<dim3(C_ / 128, B_ * L_ / 128), 256, 0, stream>>>(
        h16, Wo16, bout, out, nullptr, nullptr, nullptr, B_ * L_, C_, C_);
}

// Round 6
// 298.035 us; speedup vs baseline: 1.2260x; 1.0235x over previous
//
#include <hip/hip_runtime.h>
#include <hip/hip_bf16.h>
#include <cstdint>
#include <cstddef>

#define B_ 4
#define L_ 2048
#define C_ 1024
#define H_ 16
#define D_ 64

typedef __bf16    bf16x2 __attribute__((ext_vector_type(2)));
typedef __bf16    bf16x4 __attribute__((ext_vector_type(4)));
typedef __bf16    bf16x8 __attribute__((ext_vector_type(8)));
typedef _Float16  f16x4  __attribute__((ext_vector_type(4)));
typedef _Float16  f16x8  __attribute__((ext_vector_type(8)));
typedef float     f32x4  __attribute__((ext_vector_type(4)));
typedef float     f32x16 __attribute__((ext_vector_type(16)));
typedef uint32_t  u32x4  __attribute__((ext_vector_type(4)));

// async global->LDS, 16 B per lane. LDS dest = wave-uniform base + lane*16.
typedef const __attribute__((address_space(1))) uint32_t* gas_ptr;
typedef __attribute__((address_space(3))) uint32_t* las_ptr;
__device__ __forceinline__ void gl_lds16(const void* g, void* l) {
    __builtin_amdgcn_global_load_lds((gas_ptr)(uintptr_t)g,
                                     (las_ptr)(uintptr_t)l, 16, 0, 0);
}

// v_cvt_pk_bf16_f32: pack 2 f32 -> u32 of 2 bf16 (no builtin on gfx950, m240)
__device__ __forceinline__ uint32_t cvtpk_bf16(float lo, float hi) {
    uint32_t r;
    asm("v_cvt_pk_bf16_f32 %0, %1, %2" : "=v"(r) : "v"(lo), "v"(hi));
    return r;
}
// v_permlane32_swap_b32: a.hi <-> b.lo (VALU cross-lane, no LDS pipe)
__device__ __forceinline__ void plswap(uint32_t& a, uint32_t& b) {
    asm("v_permlane32_swap_b32 %0, %1" : "+v"(a), "+v"(b));
}

// ---------------------------------------------------------------------------
// prep kernel: region A = x fp32->fp16 (8192 blocks), region B = Wqkv
// transpose+cvt (768 blocks), region C = Wout transpose+cvt (256 blocks).
// ---------------------------------------------------------------------------
__global__ __launch_bounds__(256) void prep_kernel(
    const float* __restrict__ x, _Float16* __restrict__ x16,
    const float* __restrict__ Wqkv, _Float16* __restrict__ Wq16,
    const float* __restrict__ Wout, _Float16* __restrict__ Wo16)
{
    __shared__ float tile[64][65];
    int bid = blockIdx.x;
    const int tid = threadIdx.x;

    if (bid < 8192) {                      // cvt x
        int i = (bid * 256 + tid) * 4;
        float4 v = *(const float4*)&x[i];
        f16x4 o = {(_Float16)v.x, (_Float16)v.y, (_Float16)v.z, (_Float16)v.w};
        *(f16x4*)&x16[i] = o;
        return;
    }
    bid -= 8192;
    const float* W; _Float16* Wt; int N, tx, ty;
    if (bid < 768) { W = Wqkv; Wt = Wq16; N = 3072; tx = bid % 48; ty = bid / 48; }
    else { bid -= 768; W = Wout; Wt = Wo16; N = 1024; tx = bid % 16; ty = bid / 16; }
    const int K = 1024;
    const int k0 = ty * 64, n0 = tx * 64;
    for (int i = tid; i < 1024; i += 256) {
        int r = i >> 4, c4 = (i & 15) * 4;
        float4 v = *(const float4*)&W[(size_t)(k0 + r) * N + n0 + c4];
        tile[r][c4 + 0] = v.x; tile[r][c4 + 1] = v.y;
        tile[r][c4 + 2] = v.z; tile[r][c4 + 3] = v.w;
    }
    __syncthreads();
    for (int i = tid; i < 1024; i += 256) {
        int n = i >> 4, k4 = (i & 15) * 4;
        f16x4 o = {(_Float16)tile[k4 + 0][n], (_Float16)tile[k4 + 1][n],
                   (_Float16)tile[k4 + 2][n], (_Float16)tile[k4 + 3][n]};
        *(f16x4*)&Wt[(size_t)(n0 + n) * K + k0 + k4] = o;
    }
}

// ---------------------------------------------------------------------------
// fp16 MFMA GEMM (m97 structure).
// MODE 0: proj — fp32 out + bias.
// MODE 1: QKV fused — q/k tiles: bias + per-head RMS norm on fp32 acc
//   (q scale = log2e, k scale = sqrt(D)=8), write bf16 to qkv;
//   v tiles: bias, bf16, transpose via LDS (aliased over staging), write vT.
// ---------------------------------------------------------------------------
template <int MODE>
__global__ __launch_bounds__(256) void gemm_f16_bt_kernel(
    const _Float16* __restrict__ A, const _Float16* __restrict__ Bt,
    const float* __restrict__ bias, void* __restrict__ Cout,
    __bf16* __restrict__ vTout, const float* __restrict__ q_gamma,
    const float* __restrict__ k_gamma, int M, int N, int K)
{
    __shared__ __align__(16) char smraw[MODE == 1 ? 34816 : 16384];
    _Float16* Ash = (_Float16*)smraw;
    _Float16* Bsh = Ash + 128 * 32;

    const int tid  = threadIdx.x;
    const int lane = tid & 63;
    const int wv   = tid >> 6;
    const int wm   = wv & 1, wn = wv >> 1;
    const int n16  = lane & 15, quad = lane >> 4;
    const int brow = blockIdx.y * 128;
    const int bcol = blockIdx.x * 128;

    const int srow = lane >> 2;
    const int scol = (lane & 3) * 8;
    const _Float16* gA = A  + (size_t)(brow + wv * 32 + srow) * K + scol;
    const _Float16* gB = Bt + (size_t)(bcol + wv * 32 + srow) * K + scol;
    _Float16* lA0 = &Ash[wv * 1024];
    _Float16* lA1 = &Ash[wv * 1024 + 512];
    _Float16* lB0 = &Bsh[wv * 1024];
    _Float16* lB1 = &Bsh[wv * 1024 + 512];

    f32x4 acc[4][4] = {};

    for (int k0 = 0; k0 < K; k0 += 32) {
        gl_lds16(gA + k0,                  lA0);
        gl_lds16(gA + k0 + 16 * (size_t)K, lA1);
        gl_lds16(gB + k0,                  lB0);
        gl_lds16(gB + k0 + 16 * (size_t)K, lB1);
        __syncthreads();

        f16x8 ar[4], br[4];
        #pragma unroll
        for (int t = 0; t < 4; t++) {
            ar[t] = *(const f16x8*)&Ash[(wm * 64 + t * 16 + n16) * 32 + quad * 8];
            br[t] = *(const f16x8*)&Bsh[(wn * 64 + t * 16 + n16) * 32 + quad * 8];
        }
        #pragma unroll
        for (int i = 0; i < 4; i++)
            #pragma unroll
            for (int j = 0; j < 4; j++)
                acc[i][j] = __builtin_amdgcn_mfma_f32_16x16x32_f16(
                    ar[i], br[j], acc[i][j], 0, 0, 0);
        __syncthreads();
    }

    if (MODE == 0) {
        #pragma unroll
        for (int j = 0; j < 4; j++) {
            const int col = bcol + wn * 64 + j * 16 + n16;
            const float bv = bias[col];
            #pragma unroll
            for (int i = 0; i < 4; i++) {
                const int row0 = brow + wm * 64 + i * 16 + quad * 4;
                #pragma unroll
                for (int r = 0; r < 4; r++)
                    ((float*)Cout)[(size_t)(row0 + r) * N + col] = acc[i][j][r] + bv;
            }
        }
        return;
    }

    // ---------------- MODE 1: fused QKV epilogue ----------------
    const int region = bcol >> 10;         // 0 = q, 1 = k, 2 = v
    float bj[4];
    #pragma unroll
    for (int j = 0; j < 4; j++) bj[j] = bias[bcol + wn * 64 + j * 16 + n16];

    if (region < 2) {
        const float* gamma = (region == 0) ? q_gamma : k_gamma;
        const float scl = (region == 0) ? 1.44269504f : 8.0f;  // log2e | sqrt(D)
        const int cb = (bcol & 1023) + wn * 64 + n16;          // head-local col
        float gj[4];
        #pragma unroll
        for (int j = 0; j < 4; j++) gj[j] = gamma[cb + j * 16];

        #pragma unroll
        for (int i = 0; i < 4; i++) {
            #pragma unroll
            for (int r = 0; r < 4; r++) {
                float v0 = acc[i][0][r] + bj[0];
                float v1 = acc[i][1][r] + bj[1];
                float v2 = acc[i][2][r] + bj[2];
                float v3 = acc[i][3][r] + bj[3];
                float ss = v0 * v0 + v1 * v1 + v2 * v2 + v3 * v3;
                ss += __shfl_xor(ss, 1, 64);
                ss += __shfl_xor(ss, 2, 64);
                ss += __shfl_xor(ss, 4, 64);
                ss += __shfl_xor(ss, 8, 64);
                const float sc = scl / fmaxf(sqrtf(ss), 1e-12f);
                const int row = brow + wm * 64 + i * 16 + quad * 4 + r;
                __bf16* op = (__bf16*)Cout + (size_t)row * 3072 + bcol + wn * 64 + n16;
                op[ 0] = (__bf16)(v0 * gj[0] * sc);
                op[16] = (__bf16)(v1 * gj[1] * sc);
                op[32] = (__bf16)(v2 * gj[2] * sc);
                op[48] = (__bf16)(v3 * gj[3] * sc);
            }
        }
    } else {
        // v region: bias + bf16, transpose via LDS, store to vT[b][h][d][l]
        __syncthreads();                       // staging reads done; reuse LDS
        __bf16* LT = (__bf16*)smraw;           // [col 0..127][row 0..127] s=136
        #pragma unroll
        for (int i = 0; i < 4; i++)
            #pragma unroll
            for (int j = 0; j < 4; j++) {
                const int col = wn * 64 + j * 16 + n16;
                const int row0 = wm * 64 + i * 16 + quad * 4;
                bf16x4 t4 = {(__bf16)(acc[i][j][0] + bj[j]),
                             (__bf16)(acc[i][j][1] + bj[j]),
                             (__bf16)(acc[i][j][2] + bj[j]),
                             (__bf16)(acc[i][j][3] + bj[j])};
                *(bf16x4*)&LT[col * 136 + row0] = t4;
            }
        __syncthreads();
        const int d = tid >> 1, hf = tid & 1;
        const int bidx = brow >> 11;           // batch
        const int l0 = (brow & 2047) + hf * 64;
        const int head = ((bcol - 2048) >> 6) + (d >> 6);
        const size_t vb = (((size_t)(bidx * 16 + head)) * 64 + (d & 63)) * 2048 + l0;
        #pragma unroll
        for (int u = 0; u < 8; u++)
            *(bf16x8*)&vTout[vb + u * 8] = *(const bf16x8*)&LT[d * 136 + hf * 64 + u * 8];
    }
}

// ---------------------------------------------------------------------------
// MFMA flash attention v8: 32x32x16 MFMA + fully in-register P (T12).
// R5 post-mortem: kernel is LDS-pipe-bound (~70% busy by m134 arithmetic;
// MfmaUtil 28 / VALUBusy 37 both idle). Fix = remove LDS traffic:
//  - QK^T/PV via mfma_f32_32x32x16_bf16: S^T lane layout (q=l&31, h=l>>5,
//    k=4h+r+8m) vs PV B-frag need (k=8h+j) mismatches ONLY across l^32 ->
//    v_permlane32_swap_b32 (VALU). P = 16 cvt_pk + 8 permlane per wave per
//    64-tok tile; the entire P LDS round-trip (16 b64 w + 8 b128 r + latency)
//    is GONE. MFMA instr count halves (same FLOPs).
//  - No P scratch -> LDS = K dbuf 16K + V dbuf 16K = 32 KB, 4 blocks/CU,
//    64-token tiles -> 32 iterations (half the barriers of R5).
//  - Sync skeleton = R1/R5-proven: prefetch-at-top into buf[cur^1], ONE
//    __syncthreads per iteration. K/V staged via gl_lds with source-chunk
//    XOR swizzle (chunk ^ row&7), read back with same XOR.
// Per-lane softmax sum: lane owns 32 of 64 k per q; partner l^32 owns rest;
// ONE deferred __shfl_xor(l_run,32) at epilogue (not per-iter).
// ---------------------------------------------------------------------------
__global__ __launch_bounds__(256, 4) void attn_mfma_kernel(
    const __bf16* __restrict__ qkv, const __bf16* __restrict__ vT,
    _Float16* __restrict__ h16)
{
    const int tid  = threadIdx.x;
    const int lane = tid & 63;
    const int wv   = tid >> 6;
    const int l31  = lane & 31;
    const int h    = lane >> 5;
    const int x7   = l31 & 7;
    const int qt = blockIdx.x & 15;
    const int hh = (blockIdx.x >> 4) & 15;
    const int bb = blockIdx.x >> 8;
    const int q0 = qt * 128;
    const int bh = bb * 16 + hh;

    __shared__ __align__(16) __bf16 smem[4 * 4096];   // 32768 B
    __bf16* Kbuf = smem;                 // 2 x [64 tok][64 d], chunk-swizzled
    __bf16* Vbuf = smem + 2 * 4096;      // 2 x [64 d][64 tok], chunk-swizzled

    const __bf16* kbase = &qkv[(size_t)(bb * L_) * 3072 + 1024 + hh * 64];
    const __bf16* vbase = &vT[(size_t)bh * 64 * 2048];

    // staging: 8 lanes/row (128 B rows), rows wv*8+lr (+32 for t=1);
    // source chunk (lane&7)^(row&7), linear LDS dest (rule #21 pattern).
    const int lr = lane >> 3;
    const int lc = (lane & 7) ^ lr;
    const __bf16* kpre = kbase + (size_t)(wv * 8 + lr) * 3072 + lc * 8;
    const __bf16* vpre = vbase + (size_t)(wv * 8 + lr) * 2048 + lc * 8;
    __bf16* kdst = Kbuf + (wv * 8) * 64;
    __bf16* vdst = Vbuf + (wv * 8) * 64;

    // prologue: stage K[0], V[0] into buffer 0 (async)
    #pragma unroll
    for (int t = 0; t < 2; t++) {
        gl_lds16(kpre + (size_t)t * 32 * 3072, kdst + t * 2048);
        gl_lds16(vpre + (size_t)t * 32 * 2048, vdst + t * 2048);
    }

    // Q B-frags direct from global: lane (q=l&31) reads its own q-row,
    // d = dk*16 + h*8 + j  (4 x bf16x8, one-time)
    bf16x8 qf[4];
    const __bf16* qptr = &qkv[(size_t)(bb * L_ + q0 + wv * 32 + l31) * 3072
                              + hh * 64 + h * 8];
    #pragma unroll
    for (int dk = 0; dk < 4; dk++)
        qf[dk] = *(const bf16x8*)&qptr[dk * 16];

    f32x16 acc0 = {}, acc1 = {};
    float l_run = 0.f;

    __syncthreads();   // drains K[0], V[0]

    for (int j0 = 0, cur = 0; j0 < L_; j0 += 64, cur ^= 1) {
        // prefetch next 64-token tile into the other buffer
        if (j0 + 64 < L_) {
            #pragma unroll
            for (int t = 0; t < 2; t++) {
                gl_lds16(kpre + (size_t)(j0 + 64 + t * 32) * 3072,
                         kdst + (cur ^ 1) * 4096 + t * 2048);
                gl_lds16(vpre + (j0 + 64) + (size_t)t * 32 * 2048,
                         vdst + (cur ^ 1) * 4096 + t * 2048);
            }
        }
        const __bf16* Kc = Kbuf + cur * 4096;
        const __bf16* Vc = Vbuf + cur * 4096;

        // ---- QK^T: S^T[th] (32 tok x 32 q), k-dim = d = dk*16+8h+j ----
        f32x16 St0 = {}, St1 = {};
        __builtin_amdgcn_s_setprio(1);
        #pragma unroll
        for (int dk = 0; dk < 4; dk++) {
            const int co = ((2 * dk + h) ^ x7) * 8;
            bf16x8 k0 = *(const bf16x8*)&Kc[l31 * 64 + co];
            bf16x8 k1 = *(const bf16x8*)&Kc[(32 + l31) * 64 + co];
            St0 = __builtin_amdgcn_mfma_f32_32x32x16_bf16(k0, qf[dk], St0, 0, 0, 0);
            St1 = __builtin_amdgcn_mfma_f32_32x32x16_bf16(k1, qf[dk], St1, 0, 0, 0);
        }
        __builtin_amdgcn_s_setprio(0);

        // ---- softmax + in-register P (cvt_pk + permlane32_swap) ----
        // St[reg]: k = (reg&3) + 8*(reg>>2) + 4h  (within 32-token half)
        bf16x8 pf[4];
        float ts = 0.f;
        #pragma unroll
        for (int th = 0; th < 2; th++) {
            float e[16];
            #pragma unroll
            for (int r = 0; r < 16; r++) {
                e[r] = __builtin_amdgcn_exp2f(th == 0 ? St0[r] : St1[r]);
                ts += e[r];
            }
            uint32_t a0 = cvtpk_bf16(e[0], e[1]),  a1 = cvtpk_bf16(e[2], e[3]);
            uint32_t b0 = cvtpk_bf16(e[4], e[5]),  b1 = cvtpk_bf16(e[6], e[7]);
            plswap(a0, b0); plswap(a1, b1);
            u32x4 w0; w0.x = a0; w0.y = a1; w0.z = b0; w0.w = b1;
            pf[th * 2 + 0] = __builtin_bit_cast(bf16x8, w0);
            uint32_t c0 = cvtpk_bf16(e[8], e[9]),   c1 = cvtpk_bf16(e[10], e[11]);
            uint32_t d0 = cvtpk_bf16(e[12], e[13]), d1 = cvtpk_bf16(e[14], e[15]);
            plswap(c0, d0); plswap(c1, d1);
            u32x4 w1; w1.x = c0; w1.y = c1; w1.z = d0; w1.w = d1;
            pf[th * 2 + 1] = __builtin_bit_cast(bf16x8, w1);
        }
        l_run += ts;

        // ---- PV: O^T[dh] += V^T-frag x P-frag, k-quarter kq ----
        __builtin_amdgcn_s_setprio(1);
        #pragma unroll
        for (int kq = 0; kq < 4; kq++) {
            const int co = ((2 * kq + h) ^ x7) * 8;
            bf16x8 v0 = *(const bf16x8*)&Vc[l31 * 64 + co];
            bf16x8 v1 = *(const bf16x8*)&Vc[(32 + l31) * 64 + co];
            acc0 = __builtin_amdgcn_mfma_f32_32x32x16_bf16(v0, pf[kq], acc0, 0, 0, 0);
            acc1 = __builtin_amdgcn_mfma_f32_32x32x16_bf16(v1, pf[kq], acc1, 0, 0, 0);
        }
        __builtin_amdgcn_s_setprio(0);

        __syncthreads();   // drains prefetch vmcnt + releases buf[cur]
    }

    // partner lane (l^32) holds the complementary k-partials (linear -> defer)
    l_run += __shfl_xor(l_run, 32, 64);
    const float linv = 1.0f / l_run;

    // acc[dh][reg]: d = dh*32 + 8*(reg>>2) + 4h + (reg&3), q = l31
    const size_t orow = (size_t)(bb * L_ + q0 + wv * 32 + l31) * 1024
                        + hh * 64 + h * 4;
    #pragma unroll
    for (int m = 0; m < 4; m++) {
        f16x4 o0 = {(_Float16)(acc0[4 * m + 0] * linv),
                    (_Float16)(acc0[4 * m + 1] * linv),
                    (_Float16)(acc0[4 * m + 2] * linv),
                    (_Float16)(acc0[4 * m + 3] * linv)};
        *(f16x4*)&h16[orow + 8 * m] = o0;
        f16x4 o1 = {(_Float16)(acc1[4 * m + 0] * linv),
                    (_Float16)(acc1[4 * m + 1] * linv),
                    (_Float16)(acc1[4 * m + 2] * linv),
                    (_Float16)(acc1[4 * m + 3] * linv)};
        *(f16x4*)&h16[orow + 32 + 8 * m] = o1;
    }
}

// ---------------------------------------------------------------------------
extern "C" void kernel_launch(void* const* d_in, const int* in_sizes, int n_in,
                              void* d_out, int out_size, void* d_ws, size_t ws_size,
                              hipStream_t stream)
{
    const float* x       = (const float*)d_in[0];
    const float* Wqkv    = (const float*)d_in[1];
    const float* bqkv    = (const float*)d_in[2];
    const float* q_gamma = (const float*)d_in[3];
    const float* k_gamma = (const float*)d_in[4];
    const float* Wout    = (const float*)d_in[5];
    const float* bout    = (const float*)d_in[6];
    float* out = (float*)d_out;

    uint8_t* ws = (uint8_t*)d_ws;
    _Float16* x16   = (_Float16*)(ws);                      // 16 MB
    _Float16* Wq16  = (_Float16*)(ws + (16ull << 20));      //  6 MB
    _Float16* Wo16  = (_Float16*)(ws + (22ull << 20));      //  2 MB
    __bf16*   qkv16 = (__bf16*)  (ws + (24ull << 20));      // 48 MB (q,k used)
    _Float16* h16   = (_Float16*)(ws + (72ull << 20));      // 16 MB
    __bf16*   vT    = (__bf16*)  (ws + (88ull << 20));      // 16 MB (total 104)

    // 1) prep: x->fp16, W transposes (one launch, 3 regions)
    prep_kernel<<<8192 + 768 + 256, 256, 0, stream>>>(x, x16, Wqkv, Wq16, Wout, Wo16);

    // 2) fused QKV: GEMM + bias + RMS-norm (q,k -> qkv16 bf16) + V transpose
    gemm_f16_bt_kernel<1><<<dim3(3 * C_ / 128, B_ * L_ / 128), 256, 0, stream>>>(
        x16, Wq16, bqkv, qkv16, vT, q_gamma, k_gamma, B_ * L_, 3 * C_, C_);

    // 3) flash attention (32x32 MFMA, in-register P, 64-tok dbuf tiles) -> h16
    attn_mfma_kernel<<<B_ * H_ * (L_ / 128), 256, 0, stream>>>(qkv16, vT, h16);

    // 4) out = h @ Wout + bout -> fp32
    gemm_f16_bt_kernel<0><<<dim3(C_ / 128, B_ * L_ / 128), 256, 0, stream>>>(
        h16, Wo16, bout, out, nullptr, nullptr, nullptr, B_ * L_, C_, C_);
}